// Round 1
// baseline (718.363 us; speedup 1.0000x reference)
//
#include <hip/hip_runtime.h>
#include <hip/hip_bf16.h>

// ---------------------------------------------------------------------------
// GCN: 3x (GCNConv + ReLU) + linear classifier.
// Strategy:
//   - Build CSR-by-dst (counting sort) once per call; aggregation = per-node
//     gather loop (no float atomics in hot path).
//   - Use linearity: A(XW) == (AX)W. Aggregate on the cheaper side:
//       L1: agg(x)[256] -> GEMM(+b1,relu)
//       L2: GEMM -> agg[512](+b2,relu)
//       L3: GEMM -> agg[128](+b3,relu)
//       classifier GEMM(+bc)
//   - fp32 tiled GEMM (64x64 tile, 256 thr, 4x4 microtile, BK=16).
// ---------------------------------------------------------------------------

__global__ void init_kernel(float* __restrict__ deg, int* __restrict__ cnt,
                            int* __restrict__ pos, int n) {
    int i = blockIdx.x * blockDim.x + threadIdx.x;
    if (i < n) { deg[i] = 1.0f; cnt[i] = 0; pos[i] = 0; }  // deg starts at 1 (self loop)
}

__global__ void hist_kernel(const int* __restrict__ dst, float* __restrict__ deg,
                            int* __restrict__ cnt, int E) {
    int e = blockIdx.x * blockDim.x + threadIdx.x;
    if (e < E) {
        int d = dst[e];
        atomicAdd(&deg[d], 1.0f);
        atomicAdd(&cnt[d], 1);
    }
}

__global__ void isd_kernel(const float* __restrict__ deg, float* __restrict__ isd, int n) {
    int i = blockIdx.x * blockDim.x + threadIdx.x;
    if (i < n) isd[i] = rsqrtf(deg[i]);
}

// Exclusive scan of cnt -> row_ptr, single block of 1024 threads.
__global__ void scan_kernel(const int* __restrict__ cnt, int* __restrict__ row_ptr,
                            int n, int E) {
    __shared__ int part[1024];
    int t = threadIdx.x;
    int chunk = (n + 1023) >> 10;
    int beg = t * chunk, end = min(beg + chunk, n);
    int s = 0;
    for (int i = beg; i < end; ++i) s += cnt[i];
    part[t] = s;
    __syncthreads();
    for (int off = 1; off < 1024; off <<= 1) {
        int v = (t >= off) ? part[t - off] : 0;
        __syncthreads();
        part[t] += v;
        __syncthreads();
    }
    int run = part[t] - s;  // exclusive prefix for this chunk
    for (int i = beg; i < end; ++i) { row_ptr[i] = run; run += cnt[i]; }
    if (t == 0) row_ptr[n] = E;
}

__global__ void place_kernel(const int* __restrict__ src, const int* __restrict__ dst,
                             const float* __restrict__ isd, const int* __restrict__ row_ptr,
                             int* __restrict__ pos, int* __restrict__ s_src,
                             float* __restrict__ s_nrm, int E) {
    int e = blockIdx.x * blockDim.x + threadIdx.x;
    if (e < E) {
        int s = src[e], d = dst[e];
        int p = row_ptr[d] + atomicAdd(&pos[d], 1);
        s_src[p] = s;
        s_nrm[p] = isd[s] * isd[d];
    }
}

// Aggregate: out[i] = sum_{e in CSR(i)} xin[src[e]]*nrm[e] + xin[i]*isd[i]^2
// blockDim.x == D (feature dim). One block per node.
template <bool BIASRELU>
__global__ void agg_kernel(const float* __restrict__ xin, float* __restrict__ xout,
                           const int* __restrict__ row_ptr, const int* __restrict__ s_src,
                           const float* __restrict__ s_nrm, const float* __restrict__ isd,
                           const float* __restrict__ bias, int D) {
    int i = blockIdx.x;
    int d = threadIdx.x;
    float wself = isd[i] * isd[i];
    float acc = xin[(size_t)i * D + d] * wself;
    int beg = row_ptr[i], end = row_ptr[i + 1];
    __shared__ int   sh_s[64];
    __shared__ float sh_n[64];
    for (int c = beg; c < end; c += 64) {
        int m = min(64, end - c);
        if (threadIdx.x < m) {
            sh_s[threadIdx.x] = s_src[c + threadIdx.x];
            sh_n[threadIdx.x] = s_nrm[c + threadIdx.x];
        }
        __syncthreads();
        for (int j = 0; j < m; ++j)
            acc = fmaf(xin[(size_t)sh_s[j] * D + d], sh_n[j], acc);
        __syncthreads();
    }
    if (BIASRELU) {
        acc += bias[d];
        acc = fmaxf(acc, 0.0f);
    }
    xout[(size_t)i * D + d] = acc;
}

// C[M,N] = A[M,K] @ B[K,N] (+bias, +relu). 64x64 tile, 256 threads, 4x4/thread.
template <bool BIAS, bool RELU>
__global__ __launch_bounds__(256)
void gemm_kernel(const float* __restrict__ A, const float* __restrict__ B,
                 const float* __restrict__ bias, float* __restrict__ C,
                 int M, int K, int N) {
    const int BM = 64, BN = 64, BK = 16;
    __shared__ float As[BK][BM];  // A^T tile: As[k][m]
    __shared__ float Bs[BK][BN];
    int tid = threadIdx.x;
    int tx = tid & 15;        // n-direction (4 cols each)
    int ty = tid >> 4;        // m-direction (4 rows each)
    int bm = blockIdx.x * BM;
    int bn = blockIdx.y * BN;

    // Global-load mapping
    int arow = tid & 63;           // A row within tile
    int ak   = (tid >> 6) << 2;    // A k-offset (0,4,8,12)
    int brow = tid >> 4;           // B k-row within tile (0..15)
    int bn4  = (tid & 15) << 2;    // B col offset

    float acc[4][4] = {};

    for (int k0 = 0; k0 < K; k0 += BK) {
        float4 av;
        if (bm + arow < M)
            av = *(const float4*)(&A[(size_t)(bm + arow) * K + k0 + ak]);
        else
            av = make_float4(0.f, 0.f, 0.f, 0.f);
        As[ak + 0][arow] = av.x;
        As[ak + 1][arow] = av.y;
        As[ak + 2][arow] = av.z;
        As[ak + 3][arow] = av.w;
        float4 bv = *(const float4*)(&B[(size_t)(k0 + brow) * N + bn + bn4]);
        *(float4*)(&Bs[brow][bn4]) = bv;
        __syncthreads();
#pragma unroll
        for (int k = 0; k < BK; ++k) {
            float4 a4 = *(const float4*)(&As[k][ty << 2]);
            float4 b4 = *(const float4*)(&Bs[k][tx << 2]);
            float ar[4] = {a4.x, a4.y, a4.z, a4.w};
            float br[4] = {b4.x, b4.y, b4.z, b4.w};
#pragma unroll
            for (int mi = 0; mi < 4; ++mi)
#pragma unroll
                for (int ni = 0; ni < 4; ++ni)
                    acc[mi][ni] = fmaf(ar[mi], br[ni], acc[mi][ni]);
        }
        __syncthreads();
    }

#pragma unroll
    for (int mi = 0; mi < 4; ++mi) {
        int row = bm + (ty << 2) + mi;
        if (row < M) {
            int col = bn + (tx << 2);
            float4 v = make_float4(acc[mi][0], acc[mi][1], acc[mi][2], acc[mi][3]);
            if (BIAS) {
                v.x += bias[col + 0];
                v.y += bias[col + 1];
                v.z += bias[col + 2];
                v.w += bias[col + 3];
            }
            if (RELU) {
                v.x = fmaxf(v.x, 0.f);
                v.y = fmaxf(v.y, 0.f);
                v.z = fmaxf(v.z, 0.f);
                v.w = fmaxf(v.w, 0.f);
            }
            *(float4*)(&C[(size_t)row * N + col]) = v;
        }
    }
}

extern "C" void kernel_launch(void* const* d_in, const int* in_sizes, int n_in,
                              void* d_out, int out_size, void* d_ws, size_t ws_size,
                              hipStream_t stream) {
    const float* x  = (const float*)d_in[0];
    const int*   ei = (const int*)d_in[1];
    const float* W1 = (const float*)d_in[2];
    const float* b1 = (const float*)d_in[3];
    const float* W2 = (const float*)d_in[4];
    const float* b2 = (const float*)d_in[5];
    const float* W3 = (const float*)d_in[6];
    const float* b3 = (const float*)d_in[7];
    const float* Wc = (const float*)d_in[8];
    const float* bc = (const float*)d_in[9];
    float* out = (float*)d_out;

    const int n = in_sizes[0] / 256;   // 20000
    const int E = in_sizes[1] / 2;     // 320000
    const int* src = ei;
    const int* dst = ei + E;

    // Workspace carve-up (256B aligned regions)
    size_t off = 0;
    auto take = [&](size_t bytes) -> void* {
        void* p = (char*)d_ws + off;
        off += (bytes + 255) & ~(size_t)255;
        return p;
    };
    float* deg     = (float*)take((size_t)n * 4);
    float* isd     = (float*)take((size_t)n * 4);
    int*   cnt     = (int*)take((size_t)n * 4);
    int*   pos     = (int*)take((size_t)n * 4);
    int*   row_ptr = (int*)take((size_t)(n + 1) * 4);
    int*   s_src   = (int*)take((size_t)E * 4);
    float* s_nrm   = (float*)take((size_t)E * 4);
    float* bufA    = (float*)take((size_t)n * 1024 * 4);
    float* bufB    = (float*)take((size_t)n * 1024 * 4);

    // --- graph prep ---
    init_kernel<<<(n + 255) / 256, 256, 0, stream>>>(deg, cnt, pos, n);
    hist_kernel<<<(E + 255) / 256, 256, 0, stream>>>(dst, deg, cnt, E);
    isd_kernel<<<(n + 255) / 256, 256, 0, stream>>>(deg, isd, n);
    scan_kernel<<<1, 1024, 0, stream>>>(cnt, row_ptr, n, E);
    place_kernel<<<(E + 255) / 256, 256, 0, stream>>>(src, dst, isd, row_ptr, pos,
                                                      s_src, s_nrm, E);

    // --- Layer 1: agg(x)[256] -> GEMM(W1)+b1+relu -> bufB [n,1024] ---
    agg_kernel<false><<<n, 256, 0, stream>>>(x, bufA, row_ptr, s_src, s_nrm, isd,
                                             nullptr, 256);
    gemm_kernel<true, true><<<dim3((n + 63) / 64, 1024 / 64), 256, 0, stream>>>(
        bufA, W1, b1, bufB, n, 256, 1024);

    // --- Layer 2: GEMM(W2) -> agg[512]+b2+relu -> bufB [n,512] ---
    gemm_kernel<false, false><<<dim3((n + 63) / 64, 512 / 64), 256, 0, stream>>>(
        bufB, W2, nullptr, bufA, n, 1024, 512);
    agg_kernel<true><<<n, 512, 0, stream>>>(bufA, bufB, row_ptr, s_src, s_nrm, isd,
                                            b2, 512);

    // --- Layer 3: GEMM(W3) -> agg[128]+b3+relu -> bufB [n,128] ---
    gemm_kernel<false, false><<<dim3((n + 63) / 64, 128 / 64), 256, 0, stream>>>(
        bufB, W3, nullptr, bufA, n, 512, 128);
    agg_kernel<true><<<n, 128, 0, stream>>>(bufA, bufB, row_ptr, s_src, s_nrm, isd,
                                            b3, 128);

    // --- Classifier: GEMM(Wc)+bc -> out [n,64] ---
    gemm_kernel<true, false><<<dim3((n + 63) / 64, 64 / 64), 256, 0, stream>>>(
        bufB, Wc, bc, out, n, 128, 64);
}

// Round 2
// 321.515 us; speedup vs baseline: 2.2343x; 2.2343x over previous
//
#include <hip/hip_runtime.h>
#include <hip/hip_fp16.h>

typedef _Float16 half8 __attribute__((ext_vector_type(8)));
typedef _Float16 half4 __attribute__((ext_vector_type(4)));
typedef float floatx4 __attribute__((ext_vector_type(4)));

// ---------------------------------------------------------------------------
// GCN: 3x (GCNConv + ReLU) + classifier, fp16 MFMA GEMMs + CSR gather agg.
//   L1: agg(x)[256] -> hgemm(W1)+b1+relu
//   L2: hgemm(W2) -> agg[512]+b2+relu
//   L3: hgemm(W3) -> agg[128]+b3+relu
//   classifier hgemm(Wc)+bc -> fp32 out
// hgemm: 128x128 tile, BK=64, 4 waves, mfma_f32_16x16x32_f16, global_load_lds.
// ---------------------------------------------------------------------------

__device__ __forceinline__ void gload_lds16(const _Float16* g, _Float16* l) {
    __builtin_amdgcn_global_load_lds(
        (__attribute__((address_space(1))) void*)(g),
        (__attribute__((address_space(3))) void*)(l), 16, 0, 0);
}

// ---------------- graph prep ----------------
__global__ void init_kernel(float* __restrict__ deg, int* __restrict__ cnt,
                            int* __restrict__ pos, int n) {
    int i = blockIdx.x * blockDim.x + threadIdx.x;
    if (i < n) { deg[i] = 1.0f; cnt[i] = 0; pos[i] = 0; }
}

__global__ void hist_kernel(const int* __restrict__ dst, float* __restrict__ deg,
                            int* __restrict__ cnt, int E) {
    int e = blockIdx.x * blockDim.x + threadIdx.x;
    if (e < E) {
        int d = dst[e];
        atomicAdd(&deg[d], 1.0f);
        atomicAdd(&cnt[d], 1);
    }
}

__global__ void isd_kernel(const float* __restrict__ deg, float* __restrict__ isd, int n) {
    int i = blockIdx.x * blockDim.x + threadIdx.x;
    if (i < n) isd[i] = rsqrtf(deg[i]);
}

__global__ void scan_kernel(const int* __restrict__ cnt, int* __restrict__ row_ptr,
                            int n, int E) {
    __shared__ int part[1024];
    int t = threadIdx.x;
    int chunk = (n + 1023) >> 10;
    int beg = t * chunk, end = min(beg + chunk, n);
    int s = 0;
    for (int i = beg; i < end; ++i) s += cnt[i];
    part[t] = s;
    __syncthreads();
    for (int off = 1; off < 1024; off <<= 1) {
        int v = (t >= off) ? part[t - off] : 0;
        __syncthreads();
        part[t] += v;
        __syncthreads();
    }
    int run = part[t] - s;
    for (int i = beg; i < end; ++i) { row_ptr[i] = run; run += cnt[i]; }
    if (t == 0) row_ptr[n] = E;
}

__global__ void place_kernel(const int* __restrict__ src, const int* __restrict__ dst,
                             const float* __restrict__ isd, const int* __restrict__ row_ptr,
                             int* __restrict__ pos, int* __restrict__ s_src,
                             float* __restrict__ s_nrm, int E) {
    int e = blockIdx.x * blockDim.x + threadIdx.x;
    if (e < E) {
        int s = src[e], d = dst[e];
        int p = row_ptr[d] + atomicAdd(&pos[d], 1);
        s_src[p] = s;
        s_nrm[p] = isd[s] * isd[d];
    }
}

// ---------------- conversions ----------------
__global__ void f2h_kernel(const float4* __restrict__ in, half4* __restrict__ out, int n4) {
    int i = blockIdx.x * blockDim.x + threadIdx.x;
    if (i < n4) {
        float4 v = in[i];
        half4 o = { (_Float16)v.x, (_Float16)v.y, (_Float16)v.z, (_Float16)v.w };
        out[i] = o;
    }
}

// Wt[o][i] = W[i][o] as fp16; rows o in [fo, fo_pad) zero-filled.
__global__ void wtrans_kernel(const float* __restrict__ W, _Float16* __restrict__ Wt,
                              int fi, int fo, int fo_pad) {
    int idx = blockIdx.x * blockDim.x + threadIdx.x;
    if (idx >= fo_pad * fi) return;
    int o = idx / fi, i = idx - o * fi;
    Wt[idx] = (o < fo) ? (_Float16)W[(size_t)i * fo + o] : (_Float16)0.f;
}

// ---------------- aggregation (fp16 in/out, fp32 accumulate) ----------------
// out[i] = sum_e xin[src[e]]*nrm[e] + xin[i]*isd[i]^2 (+bias, relu)
// blockDim.x == D/2 (half2 lanes), one block per node.
template <bool BIASRELU>
__global__ void aggh_kernel(const __half2* __restrict__ xin, __half2* __restrict__ xout,
                            const int* __restrict__ row_ptr, const int* __restrict__ s_src,
                            const float* __restrict__ s_nrm, const float* __restrict__ isd,
                            const float* __restrict__ bias, int D2) {
    int i = blockIdx.x;
    int t = threadIdx.x;
    float wself = isd[i] * isd[i];
    float2 xv = __half22float2(xin[(size_t)i * D2 + t]);
    float ax = xv.x * wself, ay = xv.y * wself;
    int beg = row_ptr[i], end = row_ptr[i + 1];
    __shared__ int   sh_s[64];
    __shared__ float sh_n[64];
    for (int c = beg; c < end; c += 64) {
        int m = min(64, end - c);
        if (t < m) {
            sh_s[t] = s_src[c + t];
            sh_n[t] = s_nrm[c + t];
        }
        __syncthreads();
        for (int j = 0; j < m; ++j) {
            float2 v = __half22float2(xin[(size_t)sh_s[j] * D2 + t]);
            ax = fmaf(v.x, sh_n[j], ax);
            ay = fmaf(v.y, sh_n[j], ay);
        }
        __syncthreads();
    }
    if (BIASRELU) {
        ax = fmaxf(ax + bias[2 * t], 0.f);
        ay = fmaxf(ay + bias[2 * t + 1], 0.f);
    }
    xout[(size_t)i * D2 + t] = __floats2half2_rn(ax, ay);
}

// ---------------- fp16 MFMA GEMM ----------------
// C[M,Ncout] = A[Mpad,K] @ Bt[Npad,K]^T  (+bias, +relu)
// 128x128 tile, BK=64, 256 threads = 4 waves (2x2 quadrants of 64x64),
// each wave 4x4 fragments of 16x16, mfma_f32_16x16x32_f16.
template <bool BIAS, bool RELU, bool OUT_HALF>
__global__ __launch_bounds__(256)
void hgemm_kernel(const _Float16* __restrict__ A, const _Float16* __restrict__ Bt,
                  const float* __restrict__ bias, void* __restrict__ C,
                  int M, int K, int Ncout, int ldc) {
    __shared__ _Float16 As[128 * 64];  // [row][k]
    __shared__ _Float16 Bs[128 * 64];  // [col][k]
    const int tid = threadIdx.x;
    const int wave = tid >> 6, lane = tid & 63;
    const int l15 = lane & 15, lk = lane >> 4;   // lk in 0..3
    const int wr = wave >> 1, wc = wave & 1;     // 2x2 quadrants
    const int bm = blockIdx.x * 128, bn = blockIdx.y * 128;

    // staging source mapping: chunk c = i*256 + tid covers row (c>>3), k ((c&7)*8)
    const int srow = tid >> 3;           // + i*32 per issue
    const int sk   = (tid & 7) * 8;
    const _Float16* aSrc = A  + (size_t)(bm + srow) * K + sk;
    const _Float16* bSrc = Bt + (size_t)(bn + srow) * K + sk;

    const _Float16* aRd = As + (wr * 64 + l15) * 64 + lk * 8;
    const _Float16* bRd = Bs + (wc * 64 + l15) * 64 + lk * 8;

    floatx4 acc[4][4] = {};

    for (int k0 = 0; k0 < K; k0 += 64) {
#pragma unroll
        for (int i = 0; i < 4; ++i)
            gload_lds16(aSrc + k0 + (size_t)i * 32 * K, As + (i * 256 + wave * 64) * 8);
#pragma unroll
        for (int i = 0; i < 4; ++i)
            gload_lds16(bSrc + k0 + (size_t)i * 32 * K, Bs + (i * 256 + wave * 64) * 8);
        __syncthreads();   // drains vmcnt -> tiles in LDS
#pragma unroll
        for (int ks = 0; ks < 2; ++ks) {
            half8 af[4], bf[4];
#pragma unroll
            for (int mi = 0; mi < 4; ++mi)
                af[mi] = *(const half8*)(aRd + mi * 1024 + ks * 32);
#pragma unroll
            for (int ni = 0; ni < 4; ++ni)
                bf[ni] = *(const half8*)(bRd + ni * 1024 + ks * 32);
#pragma unroll
            for (int mi = 0; mi < 4; ++mi)
#pragma unroll
                for (int ni = 0; ni < 4; ++ni)
                    acc[mi][ni] = __builtin_amdgcn_mfma_f32_16x16x32_f16(
                        af[mi], bf[ni], acc[mi][ni], 0, 0, 0);
        }
        __syncthreads();
    }

    // epilogue: C/D layout col=lane&15, row=(lane>>4)*4+reg (m89-verified)
#pragma unroll
    for (int mi = 0; mi < 4; ++mi) {
#pragma unroll
        for (int ni = 0; ni < 4; ++ni) {
            int col  = bn + wc * 64 + ni * 16 + l15;
            int row0 = bm + wr * 64 + mi * 16 + lk * 4;
            floatx4 v = acc[mi][ni];
            if (BIAS) {
                float bb = (col < Ncout) ? bias[col] : 0.f;
                v[0] += bb; v[1] += bb; v[2] += bb; v[3] += bb;
            }
            if (RELU) {
                v[0] = fmaxf(v[0], 0.f); v[1] = fmaxf(v[1], 0.f);
                v[2] = fmaxf(v[2], 0.f); v[3] = fmaxf(v[3], 0.f);
            }
            if (col < Ncout) {
#pragma unroll
                for (int r = 0; r < 4; ++r) {
                    int row = row0 + r;
                    if (row < M) {
                        if (OUT_HALF)
                            ((__half*)C)[(size_t)row * ldc + col] = __float2half(v[r]);
                        else
                            ((float*)C)[(size_t)row * ldc + col] = v[r];
                    }
                }
            }
        }
    }
}

extern "C" void kernel_launch(void* const* d_in, const int* in_sizes, int n_in,
                              void* d_out, int out_size, void* d_ws, size_t ws_size,
                              hipStream_t stream) {
    const float* x  = (const float*)d_in[0];
    const int*   ei = (const int*)d_in[1];
    const float* W1 = (const float*)d_in[2];
    const float* b1 = (const float*)d_in[3];
    const float* W2 = (const float*)d_in[4];
    const float* b2 = (const float*)d_in[5];
    const float* W3 = (const float*)d_in[6];
    const float* b3 = (const float*)d_in[7];
    const float* Wc = (const float*)d_in[8];
    const float* bc = (const float*)d_in[9];
    float* out = (float*)d_out;

    const int n = in_sizes[0] / 256;   // 20000
    const int E = in_sizes[1] / 2;     // 320000
    const int* src = ei;
    const int* dst = ei + E;
    const int Mpad = ((n + 127) / 128) * 128;  // 20096
    const int gx = Mpad / 128;                 // 157

    size_t off = 0;
    auto take = [&](size_t bytes) -> void* {
        void* p = (char*)d_ws + off;
        off += (bytes + 255) & ~(size_t)255;
        return p;
    };
    float* deg     = (float*)take((size_t)n * 4);
    float* isd     = (float*)take((size_t)n * 4);
    int*   cnt     = (int*)take((size_t)n * 4);
    int*   pos     = (int*)take((size_t)n * 4);
    int*   row_ptr = (int*)take((size_t)(n + 1) * 4);
    int*   s_src   = (int*)take((size_t)E * 4);
    float* s_nrm   = (float*)take((size_t)E * 4);
    _Float16* xh   = (_Float16*)take((size_t)n * 256 * 2);
    _Float16* a1h  = (_Float16*)take((size_t)Mpad * 256 * 2);
    _Float16* h1h  = (_Float16*)take((size_t)Mpad * 1024 * 2);
    _Float16* g2h  = (_Float16*)take((size_t)Mpad * 512 * 2);
    _Float16* a2h  = (_Float16*)take((size_t)Mpad * 512 * 2);
    _Float16* g3h  = (_Float16*)take((size_t)Mpad * 128 * 2);
    _Float16* a3h  = (_Float16*)take((size_t)Mpad * 128 * 2);
    _Float16* w1t  = (_Float16*)take((size_t)1024 * 256 * 2);
    _Float16* w2t  = (_Float16*)take((size_t)512 * 1024 * 2);
    _Float16* w3t  = (_Float16*)take((size_t)128 * 512 * 2);
    _Float16* wct  = (_Float16*)take((size_t)128 * 128 * 2);

    // --- graph prep ---
    init_kernel<<<(n + 255) / 256, 256, 0, stream>>>(deg, cnt, pos, n);
    hist_kernel<<<(E + 255) / 256, 256, 0, stream>>>(dst, deg, cnt, E);
    isd_kernel<<<(n + 255) / 256, 256, 0, stream>>>(deg, isd, n);
    scan_kernel<<<1, 1024, 0, stream>>>(cnt, row_ptr, n, E);
    place_kernel<<<(E + 255) / 256, 256, 0, stream>>>(src, dst, isd, row_ptr, pos,
                                                      s_src, s_nrm, E);

    // --- conversions ---
    int n4 = n * 256 / 4;
    f2h_kernel<<<(n4 + 255) / 256, 256, 0, stream>>>((const float4*)x, (half4*)xh, n4);
    wtrans_kernel<<<(1024 * 256 + 255) / 256, 256, 0, stream>>>(W1, w1t, 256, 1024, 1024);
    wtrans_kernel<<<(512 * 1024 + 255) / 256, 256, 0, stream>>>(W2, w2t, 1024, 512, 512);
    wtrans_kernel<<<(128 * 512 + 255) / 256, 256, 0, stream>>>(W3, w3t, 512, 128, 128);
    wtrans_kernel<<<(128 * 128 + 255) / 256, 256, 0, stream>>>(Wc, wct, 128, 64, 128);

    // --- Layer 1: agg(xh)[256] -> GEMM(W1)+b1+relu -> h1h [n,1024] ---
    aggh_kernel<false><<<n, 128, 0, stream>>>((const __half2*)xh, (__half2*)a1h,
                                              row_ptr, s_src, s_nrm, isd, nullptr, 128);
    hgemm_kernel<true, true, true><<<dim3(gx, 8), 256, 0, stream>>>(
        a1h, w1t, b1, h1h, n, 256, 1024, 1024);

    // --- Layer 2: GEMM(W2) -> agg[512]+b2+relu -> a2h ---
    hgemm_kernel<false, false, true><<<dim3(gx, 4), 256, 0, stream>>>(
        h1h, w2t, nullptr, g2h, n, 1024, 512, 512);
    aggh_kernel<true><<<n, 256, 0, stream>>>((const __half2*)g2h, (__half2*)a2h,
                                             row_ptr, s_src, s_nrm, isd, b2, 256);

    // --- Layer 3: GEMM(W3) -> agg[128]+b3+relu -> a3h ---
    hgemm_kernel<false, false, true><<<dim3(gx, 1), 256, 0, stream>>>(
        a2h, w3t, nullptr, g3h, n, 512, 128, 128);
    aggh_kernel<true><<<n, 64, 0, stream>>>((const __half2*)g3h, (__half2*)a3h,
                                            row_ptr, s_src, s_nrm, isd, b3, 64);

    // --- Classifier: GEMM(Wc)+bc -> out [n,64] fp32 ---
    hgemm_kernel<true, false, false><<<dim3(gx, 1), 256, 0, stream>>>(
        a3h, wct, bc, out, n, 128, 64, 64);
}

// Round 3
// 292.564 us; speedup vs baseline: 2.4554x; 1.0990x over previous
//
#include <hip/hip_runtime.h>
#include <hip/hip_fp16.h>

typedef _Float16 half8 __attribute__((ext_vector_type(8)));
typedef _Float16 half4 __attribute__((ext_vector_type(4)));
typedef float floatx4 __attribute__((ext_vector_type(4)));

// ---------------------------------------------------------------------------
// GCN: 3x (GCNConv + ReLU) + classifier, fp16 MFMA GEMMs + CSR gather agg.
//   L1: agg(x)[256] -> hgemm(W1)+b1+relu        (single-buffer, 4.9 blk/CU)
//   L2: hgemm(W2) -> agg[512]+b2+relu           (dbuf pipeline, 2.45 blk/CU)
//   L3: hgemm(W3) -> agg[128]+b3+relu           (dbuf)
//   clf hgemm(Wc)+bc -> fp32 out                (dbuf)
// hgemm: 128x128 tile, BK=64, 4 waves, mfma_f32_16x16x32_f16,
//        global_load_lds w/ pre-swizzled source (T2), XCD-chunked grid (m204).
// agg:   half8/lane gather, multi-node blocks, no syncthreads, unroll-2.
// ---------------------------------------------------------------------------

__device__ __forceinline__ void gload_lds16(const _Float16* g, _Float16* l) {
    __builtin_amdgcn_global_load_lds(
        (__attribute__((address_space(1))) void*)(g),
        (__attribute__((address_space(3))) void*)(l), 16, 0, 0);
}

// ---------------- graph prep ----------------
__global__ void init_kernel(float* __restrict__ deg, int* __restrict__ cnt,
                            int* __restrict__ pos, int n) {
    int i = blockIdx.x * blockDim.x + threadIdx.x;
    if (i < n) { deg[i] = 1.0f; cnt[i] = 0; pos[i] = 0; }
}

__global__ void hist_kernel(const int* __restrict__ dst, float* __restrict__ deg,
                            int* __restrict__ cnt, int E) {
    int e = blockIdx.x * blockDim.x + threadIdx.x;
    if (e < E) {
        int d = dst[e];
        atomicAdd(&deg[d], 1.0f);
        atomicAdd(&cnt[d], 1);
    }
}

__global__ void isd_kernel(const float* __restrict__ deg, float* __restrict__ isd, int n) {
    int i = blockIdx.x * blockDim.x + threadIdx.x;
    if (i < n) isd[i] = rsqrtf(deg[i]);
}

__global__ void scan_kernel(const int* __restrict__ cnt, int* __restrict__ row_ptr,
                            int n, int E) {
    __shared__ int part[1024];
    int t = threadIdx.x;
    int chunk = (n + 1023) >> 10;
    int beg = t * chunk, end = min(beg + chunk, n);
    int s = 0;
    for (int i = beg; i < end; ++i) s += cnt[i];
    part[t] = s;
    __syncthreads();
    for (int off = 1; off < 1024; off <<= 1) {
        int v = (t >= off) ? part[t - off] : 0;
        __syncthreads();
        part[t] += v;
        __syncthreads();
    }
    int run = part[t] - s;
    for (int i = beg; i < end; ++i) { row_ptr[i] = run; run += cnt[i]; }
    if (t == 0) row_ptr[n] = E;
}

__global__ void place_kernel(const int* __restrict__ src, const int* __restrict__ dst,
                             const float* __restrict__ isd, const int* __restrict__ row_ptr,
                             int* __restrict__ pos, int* __restrict__ s_src,
                             float* __restrict__ s_nrm, int E) {
    int e = blockIdx.x * blockDim.x + threadIdx.x;
    if (e < E) {
        int s = src[e], d = dst[e];
        int p = row_ptr[d] + atomicAdd(&pos[d], 1);
        s_src[p] = s;
        s_nrm[p] = isd[s] * isd[d];
    }
}

// ---------------- conversions ----------------
__global__ void f2h_kernel(const float4* __restrict__ in, half4* __restrict__ out, int n4) {
    int i = blockIdx.x * blockDim.x + threadIdx.x;
    if (i < n4) {
        float4 v = in[i];
        half4 o = { (_Float16)v.x, (_Float16)v.y, (_Float16)v.z, (_Float16)v.w };
        out[i] = o;
    }
}

// Wt[o][i] = W[i][o] as fp16; rows o in [fo, fo_pad) zero-filled.
__global__ void wtrans_kernel(const float* __restrict__ W, _Float16* __restrict__ Wt,
                              int fi, int fo, int fo_pad) {
    int idx = blockIdx.x * blockDim.x + threadIdx.x;
    if (idx >= fo_pad * fi) return;
    int o = idx / fi, i = idx - o * fi;
    Wt[idx] = (o < fo) ? (_Float16)W[(size_t)i * fo + o] : (_Float16)0.f;
}

// ---------------- aggregation: half8/lane, LPN lanes per node ----------------
// out[i] = sum_e xin[src[e]]*nrm[e] + xin[i]*isd[i]^2 (+bias, relu)
template <int LPN, bool BIASRELU>
__global__ __launch_bounds__(256)
void aggv_kernel(const half8* __restrict__ xin, half8* __restrict__ xout,
                 const int* __restrict__ row_ptr, const int* __restrict__ s_src,
                 const float* __restrict__ s_nrm, const float* __restrict__ isd,
                 const float* __restrict__ bias, int n) {
    int t = blockIdx.x * blockDim.x + threadIdx.x;
    int i = t / LPN;
    int r = t % LPN;
    if (i >= n) return;
    float w = isd[i]; w *= w;
    half8 v = xin[(size_t)i * LPN + r];
    float a0[8], a1[8];
#pragma unroll
    for (int j = 0; j < 8; ++j) { a0[j] = (float)v[j] * w; a1[j] = 0.f; }
    int c = row_ptr[i], end = row_ptr[i + 1];
    for (; c + 2 <= end; c += 2) {
        int s0 = s_src[c], s1 = s_src[c + 1];
        float n0 = s_nrm[c], n1 = s_nrm[c + 1];
        half8 v0 = xin[(size_t)s0 * LPN + r];
        half8 v1 = xin[(size_t)s1 * LPN + r];
#pragma unroll
        for (int j = 0; j < 8; ++j) {
            a0[j] = fmaf((float)v0[j], n0, a0[j]);
            a1[j] = fmaf((float)v1[j], n1, a1[j]);
        }
    }
    if (c < end) {
        int s0 = s_src[c];
        float n0 = s_nrm[c];
        half8 v0 = xin[(size_t)s0 * LPN + r];
#pragma unroll
        for (int j = 0; j < 8; ++j) a0[j] = fmaf((float)v0[j], n0, a0[j]);
    }
    half8 o;
#pragma unroll
    for (int j = 0; j < 8; ++j) {
        float s = a0[j] + a1[j];
        if (BIASRELU) s = fmaxf(s + bias[r * 8 + j], 0.f);
        o[j] = (_Float16)s;
    }
    xout[(size_t)i * LPN + r] = o;
}

// ---------------- fp16 MFMA GEMM ----------------
// C[M,Ncout] = A[Mpad,K] @ Bt[Npad,K]^T (+bias,+relu).
// 128x128 tile, BK=64, 4 waves (2x2 quadrants), 4x4 frags of 16x16.
// LDS [row][64] with k-XOR swizzle ((row&7)<<3); staged via global_load_lds
// from pre-swizzled source addresses (linear LDS dest). 1D grid, m204 XCD map.
template <bool BIAS, bool RELU, bool OUT_HALF, bool PIPE>
__global__ __launch_bounds__(256)
void hgemm_kernel(const _Float16* __restrict__ A, const _Float16* __restrict__ Bt,
                  const float* __restrict__ bias, void* __restrict__ C,
                  int M, int K, int Ncout, int ldc, int gy) {
    __shared__ _Float16 As[PIPE ? 2 : 1][128 * 64];
    __shared__ _Float16 Bs[PIPE ? 2 : 1][128 * 64];

    // --- m204 bijective XCD-chunked grid map: consecutive logical ids (which
    // share an A-strip) land on one XCD. ---
    int nwg = gridDim.x;
    int orig = blockIdx.x;
    int q = nwg >> 3, r = nwg & 7;
    int xcd = orig & 7, seq = orig >> 3;
    int wgid = (xcd < r ? xcd * (q + 1) : r * (q + 1) + (xcd - r) * q) + seq;
    int bx = wgid / gy, by = wgid % gy;

    const int tid = threadIdx.x;
    const int wave = tid >> 6, lane = tid & 63;
    const int l15 = lane & 15, lk = lane >> 4;
    const int wr = wave >> 1, wc = wave & 1;
    const int bm = bx * 128, bn = by * 128;

    // staging: chunk c = i*256+tid -> LDS halfs [c*8, c*8+8) (linear dest).
    // logical row = c>>3, k-group = (c&7); source k pre-swizzled by row&7.
    const int srow = tid >> 3;
    const int sk_swz = (((tid & 7) ^ ((tid >> 3) & 7)) << 3);
    const _Float16* aSrc = A + (size_t)(bm + srow) * K + sk_swz;
    const _Float16* bSrc = Bt + (size_t)(bn + srow) * K + sk_swz;

    const int rowA = wr * 64 + l15;
    const int rowB = wc * 64 + l15;
    const int xorK = (l15 & 7) << 3;

    floatx4 acc[4][4] = {};

    auto STAGE = [&](int buf, int k0) {
        _Float16* la = &As[buf][wave * 512];
        _Float16* lb = &Bs[buf][wave * 512];
#pragma unroll
        for (int i = 0; i < 4; ++i)
            gload_lds16(aSrc + k0 + (size_t)i * 32 * K, la + i * 2048);
#pragma unroll
        for (int i = 0; i < 4; ++i)
            gload_lds16(bSrc + k0 + (size_t)i * 32 * K, lb + i * 2048);
    };

    auto COMPUTE = [&](int buf) {
#pragma unroll
        for (int ks = 0; ks < 2; ++ks) {
            const int kidx = ((lk << 3) + (ks << 5)) ^ xorK;
            half8 af[4], bf[4];
#pragma unroll
            for (int mi = 0; mi < 4; ++mi)
                af[mi] = *(const half8*)(&As[buf][(rowA + mi * 16) * 64 + kidx]);
#pragma unroll
            for (int ni = 0; ni < 4; ++ni)
                bf[ni] = *(const half8*)(&Bs[buf][(rowB + ni * 16) * 64 + kidx]);
#pragma unroll
            for (int mi = 0; mi < 4; ++mi)
#pragma unroll
                for (int ni = 0; ni < 4; ++ni)
                    acc[mi][ni] = __builtin_amdgcn_mfma_f32_16x16x32_f16(
                        af[mi], bf[ni], acc[mi][ni], 0, 0, 0);
        }
    };

    const int nt = K >> 6;
    if (PIPE) {
        STAGE(0, 0);
        asm volatile("s_waitcnt vmcnt(0)" ::: "memory");
        __builtin_amdgcn_s_barrier();
        for (int t = 0; t < nt; ++t) {
            int cur = t & 1;
            if (t + 1 < nt) STAGE(cur ^ 1, (t + 1) << 6);
            COMPUTE(cur);
            asm volatile("s_waitcnt vmcnt(0)" ::: "memory");
            __builtin_amdgcn_s_barrier();
        }
    } else {
        for (int t = 0; t < nt; ++t) {
            STAGE(0, t << 6);
            __syncthreads();  // drains vmcnt
            COMPUTE(0);
            __syncthreads();
        }
    }

    // epilogue: C/D layout col=lane&15, row=(lane>>4)*4+reg
#pragma unroll
    for (int mi = 0; mi < 4; ++mi) {
#pragma unroll
        for (int ni = 0; ni < 4; ++ni) {
            int col = bn + wc * 64 + ni * 16 + l15;
            int row0 = bm + wr * 64 + mi * 16 + lk * 4;
            floatx4 v = acc[mi][ni];
            if (BIAS) {
                float bb = (col < Ncout) ? bias[col] : 0.f;
                v[0] += bb; v[1] += bb; v[2] += bb; v[3] += bb;
            }
            if (RELU) {
                v[0] = fmaxf(v[0], 0.f); v[1] = fmaxf(v[1], 0.f);
                v[2] = fmaxf(v[2], 0.f); v[3] = fmaxf(v[3], 0.f);
            }
            if (col < Ncout) {
#pragma unroll
                for (int rr = 0; rr < 4; ++rr) {
                    int row = row0 + rr;
                    if (row < M) {
                        if (OUT_HALF)
                            ((__half*)C)[(size_t)row * ldc + col] = __float2half(v[rr]);
                        else
                            ((float*)C)[(size_t)row * ldc + col] = v[rr];
                    }
                }
            }
        }
    }
}

extern "C" void kernel_launch(void* const* d_in, const int* in_sizes, int n_in,
                              void* d_out, int out_size, void* d_ws, size_t ws_size,
                              hipStream_t stream) {
    const float* x  = (const float*)d_in[0];
    const int*   ei = (const int*)d_in[1];
    const float* W1 = (const float*)d_in[2];
    const float* b1 = (const float*)d_in[3];
    const float* W2 = (const float*)d_in[4];
    const float* b2 = (const float*)d_in[5];
    const float* W3 = (const float*)d_in[6];
    const float* b3 = (const float*)d_in[7];
    const float* Wc = (const float*)d_in[8];
    const float* bc = (const float*)d_in[9];
    float* out = (float*)d_out;

    const int n = in_sizes[0] / 256;   // 20000
    const int E = in_sizes[1] / 2;     // 320000
    const int* src = ei;
    const int* dst = ei + E;
    const int Mpad = ((n + 127) / 128) * 128;  // 20096
    const int gx = Mpad / 128;                 // 157

    size_t off = 0;
    auto take = [&](size_t bytes) -> void* {
        void* p = (char*)d_ws + off;
        off += (bytes + 255) & ~(size_t)255;
        return p;
    };
    float* deg     = (float*)take((size_t)n * 4);
    float* isd     = (float*)take((size_t)n * 4);
    int*   cnt     = (int*)take((size_t)n * 4);
    int*   pos     = (int*)take((size_t)n * 4);
    int*   row_ptr = (int*)take((size_t)(n + 1) * 4);
    int*   s_src   = (int*)take((size_t)E * 4);
    float* s_nrm   = (float*)take((size_t)E * 4);
    _Float16* xh   = (_Float16*)take((size_t)n * 256 * 2);
    _Float16* a1h  = (_Float16*)take((size_t)Mpad * 256 * 2);
    _Float16* h1h  = (_Float16*)take((size_t)Mpad * 1024 * 2);
    _Float16* g2h  = (_Float16*)take((size_t)Mpad * 512 * 2);
    _Float16* a2h  = (_Float16*)take((size_t)Mpad * 512 * 2);
    _Float16* g3h  = (_Float16*)take((size_t)Mpad * 128 * 2);
    _Float16* a3h  = (_Float16*)take((size_t)Mpad * 128 * 2);
    _Float16* w1t  = (_Float16*)take((size_t)1024 * 256 * 2);
    _Float16* w2t  = (_Float16*)take((size_t)512 * 1024 * 2);
    _Float16* w3t  = (_Float16*)take((size_t)128 * 512 * 2);
    _Float16* wct  = (_Float16*)take((size_t)128 * 128 * 2);

    // --- graph prep ---
    init_kernel<<<(n + 255) / 256, 256, 0, stream>>>(deg, cnt, pos, n);
    hist_kernel<<<(E + 255) / 256, 256, 0, stream>>>(dst, deg, cnt, E);
    isd_kernel<<<(n + 255) / 256, 256, 0, stream>>>(deg, isd, n);
    scan_kernel<<<1, 1024, 0, stream>>>(cnt, row_ptr, n, E);
    place_kernel<<<(E + 255) / 256, 256, 0, stream>>>(src, dst, isd, row_ptr, pos,
                                                      s_src, s_nrm, E);

    // --- conversions ---
    int n4 = n * 256 / 4;
    f2h_kernel<<<(n4 + 255) / 256, 256, 0, stream>>>((const float4*)x, (half4*)xh, n4);
    wtrans_kernel<<<(1024 * 256 + 255) / 256, 256, 0, stream>>>(W1, w1t, 256, 1024, 1024);
    wtrans_kernel<<<(512 * 1024 + 255) / 256, 256, 0, stream>>>(W2, w2t, 1024, 512, 512);
    wtrans_kernel<<<(128 * 512 + 255) / 256, 256, 0, stream>>>(W3, w3t, 512, 128, 128);
    wtrans_kernel<<<(128 * 128 + 255) / 256, 256, 0, stream>>>(Wc, wct, 128, 64, 128);

    // --- Layer 1: agg(xh)[256] -> GEMM(W1)+b1+relu -> h1h [n,1024] ---
    aggv_kernel<32, false><<<(n * 32 + 255) / 256, 256, 0, stream>>>(
        (const half8*)xh, (half8*)a1h, row_ptr, s_src, s_nrm, isd, nullptr, n);
    hgemm_kernel<true, true, true, false><<<gx * 8, 256, 0, stream>>>(
        a1h, w1t, b1, h1h, n, 256, 1024, 1024, 8);

    // --- Layer 2: GEMM(W2) -> agg[512]+b2+relu -> a2h ---
    hgemm_kernel<false, false, true, true><<<gx * 4, 256, 0, stream>>>(
        h1h, w2t, nullptr, g2h, n, 1024, 512, 512, 4);
    aggv_kernel<64, true><<<(n * 64 + 255) / 256, 256, 0, stream>>>(
        (const half8*)g2h, (half8*)a2h, row_ptr, s_src, s_nrm, isd, b2, n);

    // --- Layer 3: GEMM(W3) -> agg[128]+b3+relu -> a3h ---
    hgemm_kernel<false, false, true, true><<<gx * 1, 256, 0, stream>>>(
        a2h, w3t, nullptr, g3h, n, 512, 128, 128, 1);
    aggv_kernel<16, true><<<(n * 16 + 255) / 256, 256, 0, stream>>>(
        (const half8*)g3h, (half8*)a3h, row_ptr, s_src, s_nrm, isd, b3, n);

    // --- Classifier: GEMM(Wc)+bc -> out [n,64] fp32 ---
    hgemm_kernel<true, false, false, true><<<gx * 1, 256, 0, stream>>>(
        a3h, wct, bc, out, n, 128, 64, 64, 1);
}